// Round 24
// baseline (86.309 us; speedup 1.0000x reference)
//
#include <hip/hip_runtime.h>
#include <hip/hip_bf16.h>
#include <cstddef>

#define NH 16
#define HD 128
#define NW 4    // waves per block, splitting KV
#define NM 2    // 16-row q subtiles per wave (wave owns 32 q-rows)
#define QB 32   // q-rows per block

using short4_t = __attribute__((ext_vector_type(4))) short;
using short8_t = __attribute__((ext_vector_type(8))) short;
using f32x4    = __attribute__((ext_vector_type(4))) float;

__device__ __forceinline__ short f2bf(float f) {
    union { float f; unsigned u; } x; x.f = f;
    unsigned r = x.u + 0x7FFFu + ((x.u >> 16) & 1u);
    return (short)(r >> 16);
}

// native RNE f32->bf16: single HW cvt emitted by the compiler (m240-safe)
__device__ __forceinline__ short f2bf_n(float f) {
    union { __hip_bfloat16 h; short s; } u;
    u.h = __float2bfloat16(f);
    return u.s;
}

// async global->LDS, 16B per lane (dest = wave-uniform base + lane*16)
// EXACT form proven r8-r23; offset arg stays 0 (r16's offset-template NaN'd).
__device__ __forceinline__ void gload_lds16(const void* g, void* l) {
    __builtin_amdgcn_global_load_lds(
        (const __attribute__((address_space(1))) unsigned*)g,
        (__attribute__((address_space(3))) unsigned*)l, 16, 0, 0);
}

// ---- fused pre-pass: K,V [L][NH][HD] f32 -> Kf,Vf fragment-ordered bf16 ----
// Kf chunk (h,kt,c), elem lane: K[kt*16+(lane&15)][c*32+(lane>>4)*8 .. +7]
// Vf chunk (h,kt,cp), elem lane: j   -> V[kt*16+(lane>>4)*4+j][(2cp  )*16+(lane&15)]
//                                j+4 -> V[kt*16+(lane>>4)*4+j][(2cp+1)*16+(lane&15)]
__global__ __launch_bounds__(256) void cvt_kv_kernel(
    const float* __restrict__ K, const float* __restrict__ V,
    short* __restrict__ Kf, short* __restrict__ Vf, int L)
{
    __shared__ short lds[HD][67];
    const int h   = blockIdx.y;
    const int t0  = blockIdx.x * 64;
    const int tid = threadIdx.x;
    const int nkt = L >> 4;

    #pragma unroll
    for (int p = 0; p < 4; ++p) {
        int job = p * 256 + tid;
        int d8 = job & 15, r = job >> 4;
        const float* src = K + ((size_t)(t0 + r) * NH + h) * HD + d8 * 8;
        float4 a = ((const float4*)src)[0];
        float4 b = ((const float4*)src)[1];
        short8_t s;
        s[0] = f2bf(a.x); s[1] = f2bf(a.y); s[2] = f2bf(a.z); s[3] = f2bf(a.w);
        s[4] = f2bf(b.x); s[5] = f2bf(b.y); s[6] = f2bf(b.z); s[7] = f2bf(b.w);
        int kt = (t0 + r) >> 4, lo = (t0 + r) & 15, c = d8 >> 2, q8 = d8 & 3;
        *(short8_t*)(Kf + ((size_t)(h * nkt + kt) * 4 + c) * 512 + (q8 * 16 + lo) * 8) = s;
    }

    #pragma unroll
    for (int p = 0; p < 8; ++p) {
        int r  = p * 8 + (tid >> 5);
        int c4 = tid & 31;
        float4 v = *(const float4*)(V + ((size_t)(t0 + r) * NH + h) * HD + c4 * 4);
        lds[c4 * 4 + 0][r] = f2bf(v.x);
        lds[c4 * 4 + 1][r] = f2bf(v.y);
        lds[c4 * 4 + 2][r] = f2bf(v.z);
        lds[c4 * 4 + 3][r] = f2bf(v.w);
    }
    __syncthreads();
    #pragma unroll
    for (int it = 0; it < 4; ++it) {
        int out_id = it * 256 + tid;
        int lane = out_id & 63;
        int cp   = (out_id >> 6) & 3;
        int tt   = out_id >> 8;
        int lo = lane & 15, hi = lane >> 4;
        int tloc = tt * 16 + hi * 4;
        short8_t s;
        #pragma unroll
        for (int j = 0; j < 4; ++j) {
            s[j]     = lds[cp * 32 + lo][tloc + j];
            s[j + 4] = lds[cp * 32 + 16 + lo][tloc + j];
        }
        *(short8_t*)(Vf + ((size_t)(h * nkt + (t0 >> 4) + tt) * 4 + cp) * 512 + lane * 8) = s;
    }
}

// ---- main kernel ----
// r23 chassis EXACTLY (74.1us main, no spill, 3 waves/SIMD): NM=2, K double
// buffer 32KB + V single buffer 16KB (-> 3 blocks/CU), (256,3), exact-count
// vmcnt schedule with rule-#18 fences, lean r22 body.
// ONE change: the two per-subtile T13 votes are FUSED on the common path --
// a single __all(max(tm0-m0, tm1-m1) <= THR) (== OR of the per-subtile
// triggers); the per-subtile votes/reduces run only on the rare fail path.
// Math identical; saves one wave-level vote+branch per body on ~90% of
// bodies.
// Fragments (verified rounds 1-23):
//  S^T = mfma_16x16x32_bf16(A=K_tile, B=Q^T):  lane -> S[q=lane&15][kv=(lane>>4)*4+j]
//  O^T += mfma_16x16x16bf16_1k(A=V^T chunk, B=P^T): lane -> O[q=lane&15][d=c2*16+(lane>>4)*4+j]
template<bool PRE>
__global__ __launch_bounds__(256, 3) void varlen_attn(
    const float* __restrict__ Q, const float* __restrict__ K,
    const float* __restrict__ V, const short* __restrict__ Kf,
    const short* __restrict__ Vf, const int* __restrict__ cu,
    int n_cu, int L, int nqt, float* __restrict__ O)
{
    __shared__ short smem_k[NW][2][4][512];   // 32 KB: K double buffer
    __shared__ short smem_v[NW][4][512];      // 16 KB: V single buffer
    __shared__ float Mw[NW][QB];
    __shared__ float Lw[NW][QB];
    __shared__ float Linv[QB];

    const int tid  = threadIdx.x;
    const int w    = tid >> 6;
    const int lane = tid & 63;
    const int lo   = lane & 15;
    const int hi   = lane >> 4;
    const int nkt  = L >> 4;

    const int b  = blockIdx.x;
    const int h  = ((b & 7) << 1) | ((b >> 3) & 1);   // XCD-affine head
    const int qt = nqt - 1 - (b >> 4);                // heavy-first
    const int B  = qt * QB;                           // block q-row base

    const float qscale = 0.127517432f;   // (1/sqrt(128)) * log2(e)
    const float THR    = 11.5415605f;    // 8 * log2(e)

    int q_row[NM], seg_start[NM], ss_top[NM];
    #pragma unroll
    for (int m = 0; m < NM; ++m) {
        q_row[m] = B + m * 16 + lo;
        int ss = 0, st = 0, top = B + m * 16 + 15;
        for (int i = 1; i < n_cu; ++i) {
            int c = cu[i];
            if (c <= q_row[m]) ss = c;
            if (c <= top)      st = c;
            if (c > q_row[m] && c > top) break;
        }
        seg_start[m] = ss;
        ss_top[m]    = st;   // max seg_start over subtile rows (wave-uniform)
    }
    int ss0 = 0;
    { for (int i = 1; i < n_cu; ++i) { int c = cu[i]; if (c <= B) ss0 = c; else break; } }

    // Q fragments (scale*log2e folded in)
    short8_t qf[NM][4];
    #pragma unroll
    for (int m = 0; m < NM; ++m) {
        const float* qp = Q + ((size_t)q_row[m] * NH + h) * HD + hi * 8;
        #pragma unroll
        for (int c = 0; c < 4; ++c) {
            float4 a = *(const float4*)(qp + c * 32);
            float4 b2 = *(const float4*)(qp + c * 32 + 4);
            short8_t s;
            s[0] = f2bf_n(a.x * qscale);  s[1] = f2bf_n(a.y * qscale);
            s[2] = f2bf_n(a.z * qscale);  s[3] = f2bf_n(a.w * qscale);
            s[4] = f2bf_n(b2.x * qscale); s[5] = f2bf_n(b2.y * qscale);
            s[6] = f2bf_n(b2.z * qscale); s[7] = f2bf_n(b2.w * qscale);
            qf[m][c] = s;
        }
    }

    f32x4 o[NM][8];
    #pragma unroll
    for (int m = 0; m < NM; ++m)
        #pragma unroll
        for (int c = 0; c < 8; ++c) { o[m][c][0] = 0.f; o[m][c][1] = 0.f; o[m][c][2] = 0.f; o[m][c][3] = 0.f; }
    float mrow[NM], lrow[NM];
    #pragma unroll
    for (int m = 0; m < NM; ++m) { mrow[m] = -1e30f; lrow[m] = 0.f; }

    const int kt0 = ss0 >> 4;
    const int kt1 = (B + QB - 1) >> 4;

    // stage K chunks of tile t into K buffer kb
    auto STAGE_K = [&](int kb, int t) {
        #pragma unroll
        for (int seg = 0; seg < 4; ++seg) {
            short* dst = &smem_k[w][kb][seg][0];
            if constexpr (PRE) {
                const short* g = Kf + ((size_t)(h * nkt + t) * 4 + seg) * 512 + lane * 8;
                gload_lds16(g, dst);
            } else {
                const float* kp = K + ((size_t)(t * 16 + lo) * NH + h) * HD + seg * 32 + hi * 8;
                float4 a = ((const float4*)kp)[0];
                float4 b2 = ((const float4*)kp)[1];
                short8_t s;
                s[0] = f2bf(a.x);  s[1] = f2bf(a.y);  s[2] = f2bf(a.z);  s[3] = f2bf(a.w);
                s[4] = f2bf(b2.x); s[5] = f2bf(b2.y); s[6] = f2bf(b2.z); s[7] = f2bf(b2.w);
                *(short8_t*)(dst + lane * 8) = s;
            }
        }
    };
    // stage V chunks of tile t into the single V buffer
    auto STAGE_V = [&](int t) {
        #pragma unroll
        for (int cp = 0; cp < 4; ++cp) {
            short* dst = &smem_v[w][cp][0];
            if constexpr (PRE) {
                const short* g = Vf + ((size_t)(h * nkt + t) * 4 + cp) * 512 + lane * 8;
                gload_lds16(g, dst);
            } else {
                const float* vp = V + ((size_t)(t * 16 + hi * 4) * NH + h) * HD;
                short8_t s;
                #pragma unroll
                for (int j = 0; j < 4; ++j) {
                    s[j]     = f2bf(vp[(size_t)j * (NH * HD) + (2 * cp) * 16 + lo]);
                    s[j + 4] = f2bf(vp[(size_t)j * (NH * HD) + (2 * cp + 1) * 16 + lo]);
                }
                *(short8_t*)(dst + lane * 8) = s;
            }
        }
    };

    // ---- barrier-free per-wave pipelined KV loop (exact vmcnt counting) ----
    {
        int ktv = kt0 + w;
        if (ktv <= kt1) {
            STAGE_K(0, ktv);          // queue: [K(t0) 4]
            STAGE_V(ktv);             // queue: [K(t0) 4, V(t0) 4] = 8
            int kb = 0;
            for (; ktv <= kt1; ktv += NW) {
                const bool more = (ktv + NW <= kt1);

                if constexpr (PRE) {
                    asm volatile("s_waitcnt vmcnt(4)" ::: "memory");   // K(t) done; V(t) flies
                    __builtin_amdgcn_sched_barrier(0);
                }
                short8_t kf[4];
                #pragma unroll
                for (int c = 0; c < 4; ++c)
                    kf[c] = *(const short8_t*)&smem_k[w][kb][c][lane * 8];

                // K prefetch: kb^1 was read last body, drained by its lgkmcnt(0)
                if (more) STAGE_K(kb ^ 1, ktv + NW);

                // QK^T for both subtiles while V chunks are still in flight
                f32x4 sacc[NM];
                #pragma unroll
                for (int m = 0; m < NM; ++m) {
                    f32x4 a; a[0] = 0.f; a[1] = 0.f; a[2] = 0.f; a[3] = 0.f;
                    #pragma unroll
                    for (int c = 0; c < 4; ++c)
                        a = __builtin_amdgcn_mfma_f32_16x16x32_bf16(kf[c], qf[m][c], a, 0, 0, 0);
                    sacc[m] = a;
                }

                if constexpr (PRE) {
                    // queue: [V(t) 4, K(t+1) 4?] -> wait oldest 4 = V(t)
                    if (more) { asm volatile("s_waitcnt vmcnt(4)" ::: "memory"); }
                    else      { asm volatile("s_waitcnt vmcnt(0)" ::: "memory"); }
                    __builtin_amdgcn_sched_barrier(0);
                }
                // V fragments read directly as short4 (ds_read_b64): no unpack
                short4_t vf4[8];
                #pragma unroll
                for (int cp = 0; cp < 4; ++cp) {
                    vf4[2 * cp]     = *(const short4_t*)&smem_v[w][cp][lane * 8];
                    vf4[2 * cp + 1] = *(const short4_t*)&smem_v[w][cp][lane * 8 + 4];
                }
                asm volatile("s_waitcnt lgkmcnt(0)" ::: "memory");     // ALL lds reads sampled
                __builtin_amdgcn_sched_barrier(0);

                // V prefetch into the SAME buffer: vf4 sampled above => WAR closed
                if (more) STAGE_V(ktv + NW);

                const int k16 = ktv * 16;

                // per-subtile masked lane-max
                float tm[NM];
                bool fv[NM];
                bool validj[NM][4];
                #pragma unroll
                for (int m = 0; m < NM; ++m) {
                    fv[m] = (k16 + 15 <= B + m * 16) && (k16 >= ss_top[m]);
                    if (fv[m]) {
                        tm[m] = fmaxf(fmaxf(sacc[m][0], sacc[m][1]),
                                      fmaxf(sacc[m][2], sacc[m][3]));
                    } else {
                        tm[m] = -1e30f;
                        #pragma unroll
                        for (int j = 0; j < 4; ++j) {
                            int kidx = k16 + hi * 4 + j;
                            validj[m][j] = (kidx >= seg_start[m]) && (kidx <= q_row[m]);
                            if (validj[m][j]) tm[m] = fmaxf(tm[m], sacc[m][j]);
                        }
                    }
                }

                // FUSED T13 vote: single branch on the common path.
                // max over subtiles of (tm-m) <= THR  <==>  both per-subtile
                // conditions hold; on fail, run the exact per-subtile logic.
                if (!__all(fmaxf(tm[0] - mrow[0], tm[1] - mrow[1]) <= THR)) {
                    #pragma unroll
                    for (int m = 0; m < NM; ++m) {
                        if (!__all(tm[m] <= mrow[m] + THR)) {
                            float t = fmaxf(tm[m], __shfl_xor(tm[m], 16));
                            t = fmaxf(t, __shfl_xor(t, 32));
                            float mnew = fmaxf(mrow[m], t);
                            float sold = __builtin_exp2f(mrow[m] - mnew);
                            lrow[m] *= sold;
                            mrow[m] = mnew;
                            #pragma unroll
                            for (int c2 = 0; c2 < 8; ++c2) {
                                o[m][c2][0] *= sold; o[m][c2][1] *= sold;
                                o[m][c2][2] *= sold; o[m][c2][3] *= sold;
                            }
                        }
                    }
                }

                #pragma unroll
                for (int m = 0; m < NM; ++m) {
                    short4_t pf;
                    if (fv[m]) {
                        #pragma unroll
                        for (int j = 0; j < 4; ++j) {
                            float pj = __builtin_exp2f(sacc[m][j] - mrow[m]);
                            lrow[m] += pj;
                            pf[j] = f2bf_n(pj);
                        }
                    } else {
                        #pragma unroll
                        for (int j = 0; j < 4; ++j) {
                            float pj = validj[m][j] ? __builtin_exp2f(sacc[m][j] - mrow[m]) : 0.f;
                            lrow[m] += pj;
                            pf[j] = f2bf_n(pj);
                        }
                    }

                    #pragma unroll
                    for (int c2 = 0; c2 < 8; ++c2)
                        o[m][c2] = __builtin_amdgcn_mfma_f32_16x16x16bf16_1k(vf4[c2], pf, o[m][c2], 0, 0, 0);
                }
                kb ^= 1;
            }
            asm volatile("s_waitcnt vmcnt(0)" ::: "memory");   // safety drain
        }
    }

    // reduce lane-partial l across the row's 4 hi-groups (once per block)
    #pragma unroll
    for (int m = 0; m < NM; ++m) {
        lrow[m] += __shfl_xor(lrow[m], 16);
        lrow[m] += __shfl_xor(lrow[m], 32);
    }

    // ---- combine the NW partial (m,l,o) states (Osum overlays smem_k) ----
    if (hi == 0) {
        #pragma unroll
        for (int m = 0; m < NM; ++m) { Mw[w][m * 16 + lo] = mrow[m]; Lw[w][m * 16 + lo] = lrow[m]; }
    }
    __syncthreads();   // all waves past loop (each drained vmcnt(0)); stage dead

    float (*Osum)[132] = reinterpret_cast<float(*)[132]>(&smem_k[0][0][0][0]);

    float sc2[NM];
    #pragma unroll
    for (int m = 0; m < NM; ++m) {
        int r = m * 16 + lo;
        float M = Mw[0][r];
        #pragma unroll
        for (int ww = 1; ww < NW; ++ww) M = fmaxf(M, Mw[ww][r]);
        float Lt = 0.f;
        #pragma unroll
        for (int ww = 0; ww < NW; ++ww) Lt += Lw[ww][r] * __builtin_exp2f(Mw[ww][r] - M);
        sc2[m] = __builtin_exp2f(mrow[m] - M);
        if (w == 0 && hi == 0) Linv[r] = 1.0f / Lt;
    }

    #pragma unroll
    for (int t = 0; t < NW; ++t) {
        __syncthreads();
        if (w == t) {
            #pragma unroll
            for (int m = 0; m < NM; ++m) {
                #pragma unroll
                for (int c2 = 0; c2 < 8; ++c2) {
                    float4* dst = (float4*)&Osum[m * 16 + lo][c2 * 16 + hi * 4];
                    f32x4 v = o[m][c2];
                    float4 val;
                    val.x = v[0] * sc2[m]; val.y = v[1] * sc2[m];
                    val.z = v[2] * sc2[m]; val.w = v[3] * sc2[m];
                    if (t == 0) { *dst = val; }
                    else { float4 prev = *dst; prev.x += val.x; prev.y += val.y; prev.z += val.z; prev.w += val.w; *dst = prev; }
                }
            }
        }
    }
    __syncthreads();

    // store 32 rows x 32 float4 = 1024 chunks over 256 threads (4 iters)
    #pragma unroll
    for (int k = 0; k < 4; ++k) {
        int idx2 = k * 256 + tid;
        int r    = idx2 >> 5;          // 0..31
        int c4   = idx2 & 31;
        float4 v = *(const float4*)&Osum[r][c4 * 4];
        float li = Linv[r];
        v.x *= li; v.y *= li; v.z *= li; v.w *= li;
        *(float4*)(O + ((size_t)(B + r) * NH + h) * HD + c4 * 4) = v;
    }
}

extern "C" void kernel_launch(void* const* d_in, const int* in_sizes, int n_in,
                              void* d_out, int out_size, void* d_ws, size_t ws_size,
                              hipStream_t stream) {
    const float* Q = (const float*)d_in[0];
    const float* K = (const float*)d_in[1];
    const float* V = (const float*)d_in[2];
    const int* cu  = (const int*)d_in[3];
    int n_cu = in_sizes[3];
    int L = in_sizes[0] / (NH * HD);
    int nqt = L / QB;                      // 32-row q blocks

    const size_t elems = (size_t)NH * L * HD;
    const size_t need  = 2 * elems * sizeof(short);
    const int nblocks  = nqt * NH;

    if (ws_size >= need) {
        short* Kf = (short*)d_ws;
        short* Vf = Kf + elems;
        cvt_kv_kernel<<<dim3(L / 64, NH), 256, 0, stream>>>(K, V, Kf, Vf, L);
        varlen_attn<true><<<nblocks, 256, 0, stream>>>(
            Q, K, V, Kf, Vf, cu, n_cu, L, nqt, (float*)d_out);
    } else {
        varlen_attn<false><<<nblocks, 256, 0, stream>>>(
            Q, K, V, nullptr, nullptr, cu, n_cu, L, nqt, (float*)d_out);
    }
}

// Round 25
// 85.188 us; speedup vs baseline: 1.0132x; 1.0132x over previous
//
#include <hip/hip_runtime.h>
#include <hip/hip_bf16.h>
#include <cstddef>

#define NH 16
#define HD 128
#define NW 4    // waves per block, splitting KV
#define NM 2    // 16-row q subtiles per wave (wave owns 32 q-rows)
#define QB 32   // q-rows per block

using short4_t = __attribute__((ext_vector_type(4))) short;
using short8_t = __attribute__((ext_vector_type(8))) short;
using f32x4    = __attribute__((ext_vector_type(4))) float;

__device__ __forceinline__ short f2bf(float f) {
    union { float f; unsigned u; } x; x.f = f;
    unsigned r = x.u + 0x7FFFu + ((x.u >> 16) & 1u);
    return (short)(r >> 16);
}

// native RNE f32->bf16: single HW cvt emitted by the compiler (m240-safe)
__device__ __forceinline__ short f2bf_n(float f) {
    union { __hip_bfloat16 h; short s; } u;
    u.h = __float2bfloat16(f);
    return u.s;
}

// async global->LDS, 16B per lane (dest = wave-uniform base + lane*16)
// EXACT form proven r8-r24; offset arg stays 0 (r16's offset-template NaN'd).
__device__ __forceinline__ void gload_lds16(const void* g, void* l) {
    __builtin_amdgcn_global_load_lds(
        (const __attribute__((address_space(1))) unsigned*)g,
        (__attribute__((address_space(3))) unsigned*)l, 16, 0, 0);
}

// ---- fused pre-pass: K,V [L][NH][HD] f32 -> Kf,Vf fragment-ordered bf16 ----
// Kf chunk (h,kt,c), elem lane: K[kt*16+(lane&15)][c*32+(lane>>4)*8 .. +7]
// Vf chunk (h,kt,cp), elem lane: j   -> V[kt*16+(lane>>4)*4+j][(2cp  )*16+(lane&15)]
//                                j+4 -> V[kt*16+(lane>>4)*4+j][(2cp+1)*16+(lane&15)]
// r25: K now routed through LDS so fragment STORES are 16B/lane coalesced
// (old path scattered 16B stores at ~256B stride = ~25% store efficiency).
__global__ __launch_bounds__(256) void cvt_kv_kernel(
    const float* __restrict__ K, const float* __restrict__ V,
    short* __restrict__ Kf, short* __restrict__ Vf, int L)
{
    __shared__ short klds[64][136];   // 64 rows x 128 cols + 8-short pad (2-way bank max)
    __shared__ short vlds[HD][67];
    const int h    = blockIdx.y;
    const int t0   = blockIdx.x * 64;
    const int tid  = threadIdx.x;
    const int nkt  = L >> 4;
    const int lane = tid & 63;
    const int w    = tid >> 6;
    const int lo   = lane & 15;
    const int hi   = lane >> 4;

    // K: coalesced f32 reads -> bf16 -> LDS (row-major)
    #pragma unroll
    for (int p = 0; p < 8; ++p) {
        int r  = p * 8 + (tid >> 5);
        int c4 = tid & 31;
        float4 v = *(const float4*)(K + ((size_t)(t0 + r) * NH + h) * HD + c4 * 4);
        klds[r][c4 * 4 + 0] = f2bf(v.x);
        klds[r][c4 * 4 + 1] = f2bf(v.y);
        klds[r][c4 * 4 + 2] = f2bf(v.z);
        klds[r][c4 * 4 + 3] = f2bf(v.w);
    }
    // V: coalesced f32 reads -> bf16 -> LDS transpose
    #pragma unroll
    for (int p = 0; p < 8; ++p) {
        int r  = p * 8 + (tid >> 5);
        int c4 = tid & 31;
        float4 v = *(const float4*)(V + ((size_t)(t0 + r) * NH + h) * HD + c4 * 4);
        vlds[c4 * 4 + 0][r] = f2bf(v.x);
        vlds[c4 * 4 + 1][r] = f2bf(v.y);
        vlds[c4 * 4 + 2][r] = f2bf(v.z);
        vlds[c4 * 4 + 3][r] = f2bf(v.w);
    }
    __syncthreads();

    // K fragment stores: 16 chunks (4 kt x 4 c), 4 per wave, 16B/lane coalesced
    #pragma unroll
    for (int i = 0; i < 4; ++i) {
        int id = w * 4 + i;            // 0..15
        int kt = id >> 2, c = id & 3;
        short8_t s = *(const short8_t*)&klds[kt * 16 + lo][c * 32 + hi * 8];
        *(short8_t*)(Kf + ((size_t)(h * nkt + (t0 >> 4) + kt) * 4 + c) * 512 + lane * 8) = s;
    }

    // V fragment stores (unchanged, already coalesced)
    #pragma unroll
    for (int it = 0; it < 4; ++it) {
        int out_id = it * 256 + tid;
        int vlane = out_id & 63;
        int cp    = (out_id >> 6) & 3;
        int tt    = out_id >> 8;
        int vlo = vlane & 15, vhi = vlane >> 4;
        int tloc = tt * 16 + vhi * 4;
        short8_t s;
        #pragma unroll
        for (int j = 0; j < 4; ++j) {
            s[j]     = vlds[cp * 32 + vlo][tloc + j];
            s[j + 4] = vlds[cp * 32 + 16 + vlo][tloc + j];
        }
        *(short8_t*)(Vf + ((size_t)(h * nkt + (t0 >> 4) + tt) * 4 + cp) * 512 + vlane * 8) = s;
    }
}

// ---- main kernel ----
// r23/r24 chassis EXACTLY (74.7us main, no spill, 3 waves/SIMD): NM=2,
// K double buffer 32KB + V single buffer 16KB (-> 3 blocks/CU), (256,3),
// exact-count vmcnt schedule with rule-#18 fences, lean body, fused T13
// vote on the common path.
// Fragments (verified rounds 1-24):
//  S^T = mfma_16x16x32_bf16(A=K_tile, B=Q^T):  lane -> S[q=lane&15][kv=(lane>>4)*4+j]
//  O^T += mfma_16x16x16bf16_1k(A=V^T chunk, B=P^T): lane -> O[q=lane&15][d=c2*16+(lane>>4)*4+j]
template<bool PRE>
__global__ __launch_bounds__(256, 3) void varlen_attn(
    const float* __restrict__ Q, const float* __restrict__ K,
    const float* __restrict__ V, const short* __restrict__ Kf,
    const short* __restrict__ Vf, const int* __restrict__ cu,
    int n_cu, int L, int nqt, float* __restrict__ O)
{
    __shared__ short smem_k[NW][2][4][512];   // 32 KB: K double buffer
    __shared__ short smem_v[NW][4][512];      // 16 KB: V single buffer
    __shared__ float Mw[NW][QB];
    __shared__ float Lw[NW][QB];
    __shared__ float Linv[QB];

    const int tid  = threadIdx.x;
    const int w    = tid >> 6;
    const int lane = tid & 63;
    const int lo   = lane & 15;
    const int hi   = lane >> 4;
    const int nkt  = L >> 4;

    const int b  = blockIdx.x;
    const int h  = ((b & 7) << 1) | ((b >> 3) & 1);   // XCD-affine head
    const int qt = nqt - 1 - (b >> 4);                // heavy-first
    const int B  = qt * QB;                           // block q-row base

    const float qscale = 0.127517432f;   // (1/sqrt(128)) * log2(e)
    const float THR    = 11.5415605f;    // 8 * log2(e)

    int q_row[NM], seg_start[NM], ss_top[NM];
    #pragma unroll
    for (int m = 0; m < NM; ++m) {
        q_row[m] = B + m * 16 + lo;
        int ss = 0, st = 0, top = B + m * 16 + 15;
        for (int i = 1; i < n_cu; ++i) {
            int c = cu[i];
            if (c <= q_row[m]) ss = c;
            if (c <= top)      st = c;
            if (c > q_row[m] && c > top) break;
        }
        seg_start[m] = ss;
        ss_top[m]    = st;   // max seg_start over subtile rows (wave-uniform)
    }
    int ss0 = 0;
    { for (int i = 1; i < n_cu; ++i) { int c = cu[i]; if (c <= B) ss0 = c; else break; } }

    // Q fragments (scale*log2e folded in)
    short8_t qf[NM][4];
    #pragma unroll
    for (int m = 0; m < NM; ++m) {
        const float* qp = Q + ((size_t)q_row[m] * NH + h) * HD + hi * 8;
        #pragma unroll
        for (int c = 0; c < 4; ++c) {
            float4 a = *(const float4*)(qp + c * 32);
            float4 b2 = *(const float4*)(qp + c * 32 + 4);
            short8_t s;
            s[0] = f2bf_n(a.x * qscale);  s[1] = f2bf_n(a.y * qscale);
            s[2] = f2bf_n(a.z * qscale);  s[3] = f2bf_n(a.w * qscale);
            s[4] = f2bf_n(b2.x * qscale); s[5] = f2bf_n(b2.y * qscale);
            s[6] = f2bf_n(b2.z * qscale); s[7] = f2bf_n(b2.w * qscale);
            qf[m][c] = s;
        }
    }

    f32x4 o[NM][8];
    #pragma unroll
    for (int m = 0; m < NM; ++m)
        #pragma unroll
        for (int c = 0; c < 8; ++c) { o[m][c][0] = 0.f; o[m][c][1] = 0.f; o[m][c][2] = 0.f; o[m][c][3] = 0.f; }
    float mrow[NM], lrow[NM];
    #pragma unroll
    for (int m = 0; m < NM; ++m) { mrow[m] = -1e30f; lrow[m] = 0.f; }

    const int kt0 = ss0 >> 4;
    const int kt1 = (B + QB - 1) >> 4;

    // stage K chunks of tile t into K buffer kb
    auto STAGE_K = [&](int kb, int t) {
        #pragma unroll
        for (int seg = 0; seg < 4; ++seg) {
            short* dst = &smem_k[w][kb][seg][0];
            if constexpr (PRE) {
                const short* g = Kf + ((size_t)(h * nkt + t) * 4 + seg) * 512 + lane * 8;
                gload_lds16(g, dst);
            } else {
                const float* kp = K + ((size_t)(t * 16 + lo) * NH + h) * HD + seg * 32 + hi * 8;
                float4 a = ((const float4*)kp)[0];
                float4 b2 = ((const float4*)kp)[1];
                short8_t s;
                s[0] = f2bf(a.x);  s[1] = f2bf(a.y);  s[2] = f2bf(a.z);  s[3] = f2bf(a.w);
                s[4] = f2bf(b2.x); s[5] = f2bf(b2.y); s[6] = f2bf(b2.z); s[7] = f2bf(b2.w);
                *(short8_t*)(dst + lane * 8) = s;
            }
        }
    };
    // stage V chunks of tile t into the single V buffer
    auto STAGE_V = [&](int t) {
        #pragma unroll
        for (int cp = 0; cp < 4; ++cp) {
            short* dst = &smem_v[w][cp][0];
            if constexpr (PRE) {
                const short* g = Vf + ((size_t)(h * nkt + t) * 4 + cp) * 512 + lane * 8;
                gload_lds16(g, dst);
            } else {
                const float* vp = V + ((size_t)(t * 16 + hi * 4) * NH + h) * HD;
                short8_t s;
                #pragma unroll
                for (int j = 0; j < 4; ++j) {
                    s[j]     = f2bf(vp[(size_t)j * (NH * HD) + (2 * cp) * 16 + lo]);
                    s[j + 4] = f2bf(vp[(size_t)j * (NH * HD) + (2 * cp + 1) * 16 + lo]);
                }
                *(short8_t*)(dst + lane * 8) = s;
            }
        }
    };

    // ---- barrier-free per-wave pipelined KV loop (exact vmcnt counting) ----
    {
        int ktv = kt0 + w;
        if (ktv <= kt1) {
            STAGE_K(0, ktv);          // queue: [K(t0) 4]
            STAGE_V(ktv);             // queue: [K(t0) 4, V(t0) 4] = 8
            int kb = 0;
            for (; ktv <= kt1; ktv += NW) {
                const bool more = (ktv + NW <= kt1);

                if constexpr (PRE) {
                    asm volatile("s_waitcnt vmcnt(4)" ::: "memory");   // K(t) done; V(t) flies
                    __builtin_amdgcn_sched_barrier(0);
                }
                short8_t kf[4];
                #pragma unroll
                for (int c = 0; c < 4; ++c)
                    kf[c] = *(const short8_t*)&smem_k[w][kb][c][lane * 8];

                // K prefetch: kb^1 was read last body, drained by its lgkmcnt(0)
                if (more) STAGE_K(kb ^ 1, ktv + NW);

                // QK^T for both subtiles while V chunks are still in flight
                f32x4 sacc[NM];
                #pragma unroll
                for (int m = 0; m < NM; ++m) {
                    f32x4 a; a[0] = 0.f; a[1] = 0.f; a[2] = 0.f; a[3] = 0.f;
                    #pragma unroll
                    for (int c = 0; c < 4; ++c)
                        a = __builtin_amdgcn_mfma_f32_16x16x32_bf16(kf[c], qf[m][c], a, 0, 0, 0);
                    sacc[m] = a;
                }

                if constexpr (PRE) {
                    // queue: [V(t) 4, K(t+1) 4?] -> wait oldest 4 = V(t)
                    if (more) { asm volatile("s_waitcnt vmcnt(4)" ::: "memory"); }
                    else      { asm volatile("s_waitcnt vmcnt(0)" ::: "memory"); }
                    __builtin_amdgcn_sched_barrier(0);
                }
                // V fragments read directly as short4 (ds_read_b64): no unpack
                short4_t vf4[8];
                #pragma unroll
                for (int cp = 0; cp < 4; ++cp) {
                    vf4[2 * cp]     = *(const short4_t*)&smem_v[w][cp][lane * 8];
                    vf4[2 * cp + 1] = *(const short4_t*)&smem_v[w][cp][lane * 8 + 4];
                }
                asm volatile("s_waitcnt lgkmcnt(0)" ::: "memory");     // ALL lds reads sampled
                __builtin_amdgcn_sched_barrier(0);

                // V prefetch into the SAME buffer: vf4 sampled above => WAR closed
                if (more) STAGE_V(ktv + NW);

                const int k16 = ktv * 16;

                // per-subtile masked lane-max
                float tm[NM];
                bool fv[NM];
                bool validj[NM][4];
                #pragma unroll
                for (int m = 0; m < NM; ++m) {
                    fv[m] = (k16 + 15 <= B + m * 16) && (k16 >= ss_top[m]);
                    if (fv[m]) {
                        tm[m] = fmaxf(fmaxf(sacc[m][0], sacc[m][1]),
                                      fmaxf(sacc[m][2], sacc[m][3]));
                    } else {
                        tm[m] = -1e30f;
                        #pragma unroll
                        for (int j = 0; j < 4; ++j) {
                            int kidx = k16 + hi * 4 + j;
                            validj[m][j] = (kidx >= seg_start[m]) && (kidx <= q_row[m]);
                            if (validj[m][j]) tm[m] = fmaxf(tm[m], sacc[m][j]);
                        }
                    }
                }

                // FUSED T13 vote: single branch on the common path
                if (!__all(fmaxf(tm[0] - mrow[0], tm[1] - mrow[1]) <= THR)) {
                    #pragma unroll
                    for (int m = 0; m < NM; ++m) {
                        if (!__all(tm[m] <= mrow[m] + THR)) {
                            float t = fmaxf(tm[m], __shfl_xor(tm[m], 16));
                            t = fmaxf(t, __shfl_xor(t, 32));
                            float mnew = fmaxf(mrow[m], t);
                            float sold = __builtin_exp2f(mrow[m] - mnew);
                            lrow[m] *= sold;
                            mrow[m] = mnew;
                            #pragma unroll
                            for (int c2 = 0; c2 < 8; ++c2) {
                                o[m][c2][0] *= sold; o[m][c2][1] *= sold;
                                o[m][c2][2] *= sold; o[m][c2][3] *= sold;
                            }
                        }
                    }
                }

                #pragma unroll
                for (int m = 0; m < NM; ++m) {
                    short4_t pf;
                    if (fv[m]) {
                        #pragma unroll
                        for (int j = 0; j < 4; ++j) {
                            float pj = __builtin_exp2f(sacc[m][j] - mrow[m]);
                            lrow[m] += pj;
                            pf[j] = f2bf_n(pj);
                        }
                    } else {
                        #pragma unroll
                        for (int j = 0; j < 4; ++j) {
                            float pj = validj[m][j] ? __builtin_exp2f(sacc[m][j] - mrow[m]) : 0.f;
                            lrow[m] += pj;
                            pf[j] = f2bf_n(pj);
                        }
                    }

                    #pragma unroll
                    for (int c2 = 0; c2 < 8; ++c2)
                        o[m][c2] = __builtin_amdgcn_mfma_f32_16x16x16bf16_1k(vf4[c2], pf, o[m][c2], 0, 0, 0);
                }
                kb ^= 1;
            }
            asm volatile("s_waitcnt vmcnt(0)" ::: "memory");   // safety drain
        }
    }

    // reduce lane-partial l across the row's 4 hi-groups (once per block)
    #pragma unroll
    for (int m = 0; m < NM; ++m) {
        lrow[m] += __shfl_xor(lrow[m], 16);
        lrow[m] += __shfl_xor(lrow[m], 32);
    }

    // ---- combine the NW partial (m,l,o) states (Osum overlays smem_k) ----
    if (hi == 0) {
        #pragma unroll
        for (int m = 0; m < NM; ++m) { Mw[w][m * 16 + lo] = mrow[m]; Lw[w][m * 16 + lo] = lrow[m]; }
    }
    __syncthreads();   // all waves past loop (each drained vmcnt(0)); stage dead

    float (*Osum)[132] = reinterpret_cast<float(*)[132]>(&smem_k[0][0][0][0]);

    float sc2[NM];
    #pragma unroll
    for (int m = 0; m < NM; ++m) {
        int r = m * 16 + lo;
        float M = Mw[0][r];
        #pragma unroll
        for (int ww = 1; ww < NW; ++ww) M = fmaxf(M, Mw[ww][r]);
        float Lt = 0.f;
        #pragma unroll
        for (int ww = 0; ww < NW; ++ww) Lt += Lw[ww][r] * __builtin_exp2f(Mw[ww][r] - M);
        sc2[m] = __builtin_exp2f(mrow[m] - M);
        if (w == 0 && hi == 0) Linv[r] = 1.0f / Lt;
    }

    #pragma unroll
    for (int t = 0; t < NW; ++t) {
        __syncthreads();
        if (w == t) {
            #pragma unroll
            for (int m = 0; m < NM; ++m) {
                #pragma unroll
                for (int c2 = 0; c2 < 8; ++c2) {
                    float4* dst = (float4*)&Osum[m * 16 + lo][c2 * 16 + hi * 4];
                    f32x4 v = o[m][c2];
                    float4 val;
                    val.x = v[0] * sc2[m]; val.y = v[1] * sc2[m];
                    val.z = v[2] * sc2[m]; val.w = v[3] * sc2[m];
                    if (t == 0) { *dst = val; }
                    else { float4 prev = *dst; prev.x += val.x; prev.y += val.y; prev.z += val.z; prev.w += val.w; *dst = prev; }
                }
            }
        }
    }
    __syncthreads();

    // store 32 rows x 32 float4 = 1024 chunks over 256 threads (4 iters)
    #pragma unroll
    for (int k = 0; k < 4; ++k) {
        int idx2 = k * 256 + tid;
        int r    = idx2 >> 5;          // 0..31
        int c4   = idx2 & 31;
        float4 v = *(const float4*)&Osum[r][c4 * 4];
        float li = Linv[r];
        v.x *= li; v.y *= li; v.z *= li; v.w *= li;
        *(float4*)(O + ((size_t)(B + r) * NH + h) * HD + c4 * 4) = v;
    }
}

extern "C" void kernel_launch(void* const* d_in, const int* in_sizes, int n_in,
                              void* d_out, int out_size, void* d_ws, size_t ws_size,
                              hipStream_t stream) {
    const float* Q = (const float*)d_in[0];
    const float* K = (const float*)d_in[1];
    const float* V = (const float*)d_in[2];
    const int* cu  = (const int*)d_in[3];
    int n_cu = in_sizes[3];
    int L = in_sizes[0] / (NH * HD);
    int nqt = L / QB;                      // 32-row q blocks

    const size_t elems = (size_t)NH * L * HD;
    const size_t need  = 2 * elems * sizeof(short);
    const int nblocks  = nqt * NH;

    if (ws_size >= need) {
        short* Kf = (short*)d_ws;
        short* Vf = Kf + elems;
        cvt_kv_kernel<<<dim3(L / 64, NH), 256, 0, stream>>>(K, V, Kf, Vf, L);
        varlen_attn<true><<<nblocks, 256, 0, stream>>>(
            Q, K, V, Kf, Vf, cu, n_cu, L, nqt, (float*)d_out);
    } else {
        varlen_attn<false><<<nblocks, 256, 0, stream>>>(
            Q, K, V, nullptr, nullptr, cu, n_cu, L, nqt, (float*)d_out);
    }
}